// Round 5
// baseline (387.970 us; speedup 1.0000x reference)
//
#include <hip/hip_runtime.h>

#define BLK 256
#define SB_SHIFT 7          // 128 dst per bucket
#define NBMAX 576
#define CHUNK_E 4096

// ---------------- generic zero ----------------

__global__ void zero_kernel(int* __restrict__ p, int n) {
    int i = blockIdx.x * blockDim.x + threadIdx.x;
    if (i < n) p[i] = 0;
}

// ---------------- bucketed CSR build ----------------

struct BJobs {
    const int* src[3];
    const int* dst[3];
    int E[3];
    int Eoff[4];       // concat edge offsets per relation
    int nboff[4];      // concat bucket-id offsets per relation
    int ndst[3];
    int Roff[3];       // row_ptr concat offsets per relation
    int chunk_off[4];  // chunk-block offsets per relation
};

__launch_bounds__(BLK)
__global__ void bhist_kernel(BJobs J, int* __restrict__ gcnt, int NB) {
    __shared__ int lc[NBMAX];
    int tid = threadIdx.x;
    for (int i = tid; i < NB; i += BLK) lc[i] = 0;
    __syncthreads();
    int b = blockIdx.x, r = 0;
    while (b >= J.chunk_off[r + 1]) ++r;
    int e0 = (b - J.chunk_off[r]) * CHUNK_E;
    int e1 = min(e0 + CHUNK_E, J.E[r]);
    const int* __restrict__ dst = J.dst[r];
    int base = J.nboff[r];
    for (int e = e0 + tid; e < e1; e += BLK)
        atomicAdd(&lc[base + (dst[e] >> SB_SHIFT)], 1);
    __syncthreads();
    for (int i = tid; i < NB; i += BLK)
        if (lc[i]) atomicAdd(&gcnt[i], lc[i]);
}

// Block-wide exclusive scan (256 threads, 16 items/thread/chunk).
__device__ void scan_block(const int* __restrict__ cnt, int* __restrict__ row,
                           int* __restrict__ cur, int n) {
    __shared__ int wsum[4];
    __shared__ int s_carry;
    const int ITEMS = 16;
    const int CHUNK = BLK * ITEMS;
    int lane = threadIdx.x & 63;
    int wv = threadIdx.x >> 6;
    if (threadIdx.x == 0) s_carry = 0;
    __syncthreads();
    for (int base = 0; base < n; base += CHUNK) {
        int idx0 = base + threadIdx.x * ITEMS;
        int v[ITEMS];
        int tsum = 0;
#pragma unroll
        for (int j = 0; j < ITEMS; ++j) {
            int i = idx0 + j;
            v[j] = (i < n) ? cnt[i] : 0;
            tsum += v[j];
        }
        int incl = tsum;
#pragma unroll
        for (int off = 1; off < 64; off <<= 1) {
            int t = __shfl_up(incl, off);
            if (lane >= off) incl += t;
        }
        if (lane == 63) wsum[wv] = incl;
        __syncthreads();
        int carry = s_carry;
        int woff = 0;
        for (int w = 0; w < wv; ++w) woff += wsum[w];
        int excl = carry + woff + (incl - tsum);
#pragma unroll
        for (int j = 0; j < ITEMS; ++j) {
            int i = idx0 + j;
            if (i < n) { row[i] = excl; cur[i] = excl; }
            excl += v[j];
        }
        __syncthreads();
        if (threadIdx.x == 0) s_carry = carry + wsum[0] + wsum[1] + wsum[2] + wsum[3];
        __syncthreads();
    }
    if (threadIdx.x == 0) row[n] = s_carry;
}

__global__ void bscan_kernel(const int* __restrict__ gcnt, int* __restrict__ bbase,
                             int* __restrict__ bcur, int n) {
    scan_block(gcnt, bbase, bcur, n);
}

__launch_bounds__(BLK)
__global__ void bbin_kernel(BJobs J, int* __restrict__ bcur, int2* __restrict__ ebuf, int NB) {
    __shared__ int lc[NBMAX];
    __shared__ int res[NBMAX];
    __shared__ int cur[NBMAX];
    int tid = threadIdx.x;
    for (int i = tid; i < NB; i += BLK) { lc[i] = 0; cur[i] = 0; }
    __syncthreads();
    int b = blockIdx.x, r = 0;
    while (b >= J.chunk_off[r + 1]) ++r;
    int e0 = (b - J.chunk_off[r]) * CHUNK_E;
    int e1 = min(e0 + CHUNK_E, J.E[r]);
    const int* __restrict__ src = J.src[r];
    const int* __restrict__ dst = J.dst[r];
    int base = J.nboff[r];
    for (int e = e0 + tid; e < e1; e += BLK)
        atomicAdd(&lc[base + (dst[e] >> SB_SHIFT)], 1);
    __syncthreads();
    for (int i = tid; i < NB; i += BLK)
        if (lc[i]) res[i] = atomicAdd(&bcur[i], lc[i]);
    __syncthreads();
    for (int e = e0 + tid; e < e1; e += BLK) {
        int s = src[e], d = dst[e];
        int bk = base + (d >> SB_SHIFT);
        int l = atomicAdd(&cur[bk], 1);
        ebuf[res[bk] + l] = make_int2(s, d);
    }
}

// One block per bucket: per-dst count, 128-wide scan, write row_ptr, place edges.
__launch_bounds__(BLK)
__global__ void bplace_kernel(BJobs J, const int* __restrict__ bbase,
                              const int2* __restrict__ ebuf,
                              int* __restrict__ ccsr, int* __restrict__ rowcat) {
    __shared__ int cnt[128];
    __shared__ int off[128];
    __shared__ int cur[128];
    int tid = threadIdx.x;
    int bk = blockIdx.x, r = 0;
    while (bk >= J.nboff[r + 1]) ++r;
    int dst0 = (bk - J.nboff[r]) << SB_SHIFT;
    int nd = J.ndst[r] - dst0;
    if (nd > 128) nd = 128;
    int ebase = bbase[bk], eend = bbase[bk + 1];
    if (tid < 128) cnt[tid] = 0;
    __syncthreads();
    for (int e = ebase + tid; e < eend; e += BLK)
        atomicAdd(&cnt[ebuf[e].y - dst0], 1);
    __syncthreads();
    if (tid < 128) off[tid] = cnt[tid];
    __syncthreads();
    for (int st = 1; st < 128; st <<= 1) {
        int v = 0;
        if (tid < 128 && tid >= st) v = off[tid - st];
        __syncthreads();
        if (tid < 128) off[tid] += v;
        __syncthreads();
    }
    int Eo = J.Eoff[r];
    int* __restrict__ row = rowcat + J.Roff[r];
    if (tid < nd) {
        int ex = off[tid] - cnt[tid];           // exclusive within-bucket offset
        row[dst0 + tid] = ebase + ex - Eo;      // relation-relative
        cur[tid] = ex;
    }
    if (tid == 0 && dst0 + nd == J.ndst[r])
        row[J.ndst[r]] = bbase[J.nboff[r + 1]] - Eo;
    __syncthreads();
    for (int e = ebase + tid; e < eend; e += BLK) {
        int2 sd = ebuf[e];
        int l = atomicAdd(&cur[sd.y - dst0], 1);
        ccsr[ebase + l] = sd.x;
    }
}

// ---------------- Dense transform: y = x @ W^T (+ b) ----------------
// Lane = output channel h. W row (64 floats) held in 16 float4 registers,
// staged via conflict-free LDS. Per node: coalesced 256B x-row load ->
// wave-local LDS bounce -> 16 broadcast ds_read_b128 + 64 FMA (4-node unroll).

struct TJobs {
    const float* x[6];
    const float* W[6];
    const float* b[6];
    float* y[6];
    int n[6];
    int boff[7];
};

__launch_bounds__(BLK)
__global__ void transform_kernel(TJobs J) {
    __shared__ float4 WT4[1024];        // [dq][h], 16KB
    __shared__ float4 xrow[4][4][16];   // [wave][node_sub][quad], 4KB
    int b = blockIdx.x, j = 0;
    while (b >= J.boff[j + 1]) ++j;
    int n = J.n[j];
    const float4* __restrict__ x4 = (const float4*)J.x[j];
    const float4* __restrict__ W4 = (const float4*)J.W[j];
    const float* bb = J.b[j];
    float* __restrict__ y = J.y[j];
    int tid = threadIdx.x, lane = tid & 63, wv = tid >> 6;

    // stage W: wave wv handles dq = wv*4..wv*4+3; lanes = h -> conflict-free
#pragma unroll
    for (int t = 0; t < 4; ++t) {
        int dq = wv * 4 + t;
        WT4[dq * 64 + lane] = W4[lane * 16 + dq];   // W[h=lane][dq*4..+3]
    }
    __syncthreads();
    float4 Wreg[16];
#pragma unroll
    for (int dq = 0; dq < 16; ++dq) Wreg[dq] = WT4[dq * 64 + lane];
    float bias = bb ? bb[lane] : 0.f;

    int nb0 = (b - J.boff[j]) * 64 + wv * 16;   // this wave's 16 nodes

#pragma unroll
    for (int it = 0; it < 4; ++it) {
        int nodeL = nb0 + it * 4 + (lane >> 4);   // lanes 0-15 -> node+0, ... 48-63 -> node+3
        int q = lane & 15;
        float4 v = make_float4(0.f, 0.f, 0.f, 0.f);
        if (nodeL < n) v = x4[(size_t)nodeL * 16 + q];
        xrow[wv][lane >> 4][q] = v;               // wave-coherent, no __syncthreads needed
        float o0 = bias, o1 = bias, o2 = bias, o3 = bias;
#pragma unroll
        for (int dq = 0; dq < 16; ++dq) {
            float4 w = Wreg[dq];
            float4 m0 = xrow[wv][0][dq];
            float4 m1 = xrow[wv][1][dq];
            float4 m2 = xrow[wv][2][dq];
            float4 m3 = xrow[wv][3][dq];
            o0 += w.x * m0.x + w.y * m0.y + w.z * m0.z + w.w * m0.w;
            o1 += w.x * m1.x + w.y * m1.y + w.z * m1.z + w.w * m1.w;
            o2 += w.x * m2.x + w.y * m2.y + w.z * m2.z + w.w * m2.w;
            o3 += w.x * m3.x + w.y * m3.y + w.z * m3.z + w.w * m3.w;
        }
        int nd0 = nb0 + it * 4;
        if (nd0 + 0 < n) y[(size_t)(nd0 + 0) * 64 + lane] = o0;
        if (nd0 + 1 < n) y[(size_t)(nd0 + 1) * 64 + lane] = o1;
        if (nd0 + 2 < n) y[(size_t)(nd0 + 2) * 64 + lane] = o2;
        if (nd0 + 3 < n) y[(size_t)(nd0 + 3) * 64 + lane] = o3;
    }
}

// ---------------- Gather-mean + add (RMW into out), 8-way unrolled ----------------

struct GJobs {
    const float* y[3];
    const int* row[3];
    const int* csr[3];
    float* out[3];
    int n[3];
    int boff[4];
    int relu;
};

__launch_bounds__(BLK)
__global__ void gather_kernel(GJobs J) {
    int b = blockIdx.x, j = 0;
    while (b >= J.boff[j + 1]) ++j;
    int lane = threadIdx.x & 63, wv = threadIdx.x >> 6;
    int node = (b - J.boff[j]) * 4 + wv;
    if (node >= J.n[j]) return;
    const int* __restrict__ row = J.row[j];
    const int* __restrict__ csr = J.csr[j];
    const float* __restrict__ y = J.y[j];
    float* __restrict__ out = J.out[j];

    int e0 = row[node], e1 = row[node + 1];
    float a0 = 0.f, a1 = 0.f, a2 = 0.f, a3 = 0.f;
    float a4 = 0.f, a5 = 0.f, a6 = 0.f, a7 = 0.f;
    int e = e0;
    for (; e + 8 <= e1; e += 8) {
        int s0 = csr[e + 0], s1 = csr[e + 1], s2 = csr[e + 2], s3 = csr[e + 3];
        int s4 = csr[e + 4], s5 = csr[e + 5], s6 = csr[e + 6], s7 = csr[e + 7];
        a0 += y[(size_t)s0 * 64 + lane];
        a1 += y[(size_t)s1 * 64 + lane];
        a2 += y[(size_t)s2 * 64 + lane];
        a3 += y[(size_t)s3 * 64 + lane];
        a4 += y[(size_t)s4 * 64 + lane];
        a5 += y[(size_t)s5 * 64 + lane];
        a6 += y[(size_t)s6 * 64 + lane];
        a7 += y[(size_t)s7 * 64 + lane];
    }
    for (; e < e1; ++e) a0 += y[(size_t)csr[e] * 64 + lane];
    int deg = e1 - e0;
    float m = ((a0 + a1) + (a2 + a3)) + ((a4 + a5) + (a6 + a7));
    m = deg ? m / (float)deg : 0.f;
    size_t oi = (size_t)node * 64 + lane;
    float o = m + out[oi];
    if (J.relu) o = fmaxf(o, 0.f);
    out[oi] = o;
}

// ---------------- Host ----------------

extern "C" void kernel_launch(void* const* d_in, const int* in_sizes, int n_in,
                              void* d_out, int out_size, void* d_ws, size_t ws_size,
                              hipStream_t stream) {
    const float* x_user    = (const float*)d_in[0];
    const float* x_problem = (const float*)d_in[1];
    const float* x_topic   = (const float*)d_in[2];
    const int* up_src = (const int*)d_in[3];
    const int* up_dst = (const int*)d_in[4];
    const int* pt_src = (const int*)d_in[5];
    const int* pt_dst = (const int*)d_in[6];
    const int* pu_src = (const int*)d_in[7];
    const int* pu_dst = (const int*)d_in[8];
    const float* W1_up_l = (const float*)d_in[9];
    const float* W1_up_r = (const float*)d_in[10];
    const float* W1_pt_l = (const float*)d_in[11];
    const float* W1_pt_r = (const float*)d_in[12];
    const float* W1_pu_l = (const float*)d_in[13];
    const float* W1_pu_r = (const float*)d_in[14];
    const float* W2_up_l = (const float*)d_in[15];
    const float* W2_up_r = (const float*)d_in[16];
    const float* W2_pt_l = (const float*)d_in[17];
    const float* W2_pt_r = (const float*)d_in[18];
    const float* W2_pu_l = (const float*)d_in[19];
    const float* W2_pu_r = (const float*)d_in[20];
    const float* b1_up = (const float*)d_in[21];
    const float* b1_pt = (const float*)d_in[22];
    const float* b1_pu = (const float*)d_in[23];
    const float* b2_up = (const float*)d_in[24];
    const float* b2_pt = (const float*)d_in[25];
    const float* b2_pu = (const float*)d_in[26];

    int n_user = in_sizes[0] / 64;
    int n_problem = in_sizes[1] / 64;
    int n_topic = in_sizes[2] / 64;
    int E_up = in_sizes[3];
    int E_pt = in_sizes[5];
    int E_pu = in_sizes[7];
    int E_tot = E_up + E_pt + E_pu;

    float* o_user = (float*)d_out;
    float* o_problem = o_user + (size_t)n_user * 64;
    float* o_topic = o_problem + (size_t)n_problem * 64;

    char* ws = (char*)d_ws;
    size_t off = 0;
    auto alloc = [&](size_t bytes) -> void* {
        void* p = ws + off;
        off += (bytes + 255) & ~(size_t)255;
        return p;
    };
    float* h_user    = (float*)alloc((size_t)n_user * 64 * 4);
    float* h_problem = (float*)alloc((size_t)n_problem * 64 * 4);
    float* h_topic   = (float*)alloc((size_t)n_topic * 64 * 4);
    // y buffers; the front of this region doubles as ebuf (int2 per edge) during CSR build
    float* y_up = (float*)alloc((size_t)n_user * 64 * 4);
    float* y_pt = (float*)alloc((size_t)n_problem * 64 * 4);
    float* y_pu = (float*)alloc((size_t)n_problem * 64 * 4);
    int2* ebuf = (int2*)y_up;  // 16.5MB needed, 23MB available before first transform

    auto cdiv = [](int a, int b) { return (a + b - 1) / b; };

    // buckets: relations ordered [up(dst=problem), pt(dst=topic), pu(dst=user)]
    int nb0 = cdiv(n_problem, 128), nb1 = cdiv(n_topic, 128), nb2 = cdiv(n_user, 128);
    int NB = nb0 + nb1 + nb2;

    int* gcnt  = (int*)alloc((size_t)(NB) * 4);
    int* bbase = (int*)alloc((size_t)(NB + 1) * 4);
    int* bcur  = (int*)alloc((size_t)(NB + 1) * 4);
    int* rowcat = (int*)alloc((size_t)(n_problem + n_topic + n_user + 3) * 4);
    int* ccsr  = (int*)alloc((size_t)E_tot * 4);

    BJobs B;
    B.src[0] = up_src; B.dst[0] = up_dst; B.E[0] = E_up;
    B.src[1] = pt_src; B.dst[1] = pt_dst; B.E[1] = E_pt;
    B.src[2] = pu_src; B.dst[2] = pu_dst; B.E[2] = E_pu;
    B.Eoff[0] = 0; B.Eoff[1] = E_up; B.Eoff[2] = E_up + E_pt; B.Eoff[3] = E_tot;
    B.nboff[0] = 0; B.nboff[1] = nb0; B.nboff[2] = nb0 + nb1; B.nboff[3] = NB;
    B.ndst[0] = n_problem; B.ndst[1] = n_topic; B.ndst[2] = n_user;
    B.Roff[0] = 0; B.Roff[1] = n_problem + 1; B.Roff[2] = n_problem + 1 + n_topic + 1;
    B.chunk_off[0] = 0;
    for (int r = 0; r < 3; ++r) B.chunk_off[r + 1] = B.chunk_off[r] + cdiv(B.E[r], CHUNK_E);

    const int* row_up = rowcat + B.Roff[0];
    const int* row_pt = rowcat + B.Roff[1];
    const int* row_pu = rowcat + B.Roff[2];
    const int* csr_up = ccsr + B.Eoff[0];
    const int* csr_pt = ccsr + B.Eoff[1];
    const int* csr_pu = ccsr + B.Eoff[2];

    zero_kernel<<<cdiv(NB, 256), 256, 0, stream>>>(gcnt, NB);
    bhist_kernel<<<B.chunk_off[3], BLK, 0, stream>>>(B, gcnt, NB);
    bscan_kernel<<<1, BLK, 0, stream>>>(gcnt, bbase, bcur, NB);
    bbin_kernel<<<B.chunk_off[3], BLK, 0, stream>>>(B, bcur, ebuf, NB);
    bplace_kernel<<<B.nboff[3], BLK, 0, stream>>>(B, bbase, ebuf, ccsr, rowcat);

    // ---- layer 1 ----
    {
        TJobs T;
        const float* xs[6] = {x_user, x_problem, x_problem, x_problem, x_topic, x_user};
        const float* Ws[6] = {W1_up_l, W1_pt_l, W1_pu_l, W1_up_r, W1_pt_r, W1_pu_r};
        const float* bs[6] = {nullptr, nullptr, nullptr, b1_up, b1_pt, b1_pu};
        float* ys[6] = {y_up, y_pt, y_pu, h_problem, h_topic, h_user};
        int ns[6] = {n_user, n_problem, n_problem, n_problem, n_topic, n_user};
        T.boff[0] = 0;
        for (int j = 0; j < 6; ++j) {
            T.x[j] = xs[j]; T.W[j] = Ws[j]; T.b[j] = bs[j]; T.y[j] = ys[j]; T.n[j] = ns[j];
            T.boff[j + 1] = T.boff[j] + cdiv(ns[j], 64);
        }
        transform_kernel<<<T.boff[6], BLK, 0, stream>>>(T);

        GJobs G;
        const float* gy[3] = {y_pu, y_up, y_pt};
        const int* gr[3] = {row_pu, row_up, row_pt};
        const int* gc[3] = {csr_pu, csr_up, csr_pt};
        float* go[3] = {h_user, h_problem, h_topic};
        int gn[3] = {n_user, n_problem, n_topic};
        G.boff[0] = 0;
        for (int j = 0; j < 3; ++j) {
            G.y[j] = gy[j]; G.row[j] = gr[j]; G.csr[j] = gc[j]; G.out[j] = go[j]; G.n[j] = gn[j];
            G.boff[j + 1] = G.boff[j] + cdiv(gn[j], 4);
        }
        G.relu = 1;
        gather_kernel<<<G.boff[3], BLK, 0, stream>>>(G);
    }

    // ---- layer 2 ----
    {
        TJobs T;
        const float* xs[6] = {h_user, h_problem, h_problem, h_problem, h_topic, h_user};
        const float* Ws[6] = {W2_up_l, W2_pt_l, W2_pu_l, W2_up_r, W2_pt_r, W2_pu_r};
        const float* bs[6] = {nullptr, nullptr, nullptr, b2_up, b2_pt, b2_pu};
        float* ys[6] = {y_up, y_pt, y_pu, o_problem, o_topic, o_user};
        int ns[6] = {n_user, n_problem, n_problem, n_problem, n_topic, n_user};
        T.boff[0] = 0;
        for (int j = 0; j < 6; ++j) {
            T.x[j] = xs[j]; T.W[j] = Ws[j]; T.b[j] = bs[j]; T.y[j] = ys[j]; T.n[j] = ns[j];
            T.boff[j + 1] = T.boff[j] + cdiv(ns[j], 64);
        }
        transform_kernel<<<T.boff[6], BLK, 0, stream>>>(T);

        GJobs G;
        const float* gy[3] = {y_pu, y_up, y_pt};
        const int* gr[3] = {row_pu, row_up, row_pt};
        const int* gc[3] = {csr_pu, csr_up, csr_pt};
        float* go[3] = {o_user, o_problem, o_topic};
        int gn[3] = {n_user, n_problem, n_topic};
        G.boff[0] = 0;
        for (int j = 0; j < 3; ++j) {
            G.y[j] = gy[j]; G.row[j] = gr[j]; G.csr[j] = gc[j]; G.out[j] = go[j]; G.n[j] = gn[j];
            G.boff[j + 1] = G.boff[j] + cdiv(gn[j], 4);
        }
        G.relu = 0;
        gather_kernel<<<G.boff[3], BLK, 0, stream>>>(G);
    }
}